// Round 3
// baseline (188.201 us; speedup 1.0000x reference)
//
#include <hip/hip_runtime.h>

#define NRBF 20
#define FOUT 16
#define NA 768
#define NB 4

__global__ __launch_bounds__(256) void cfconv_kernel(
    const float* __restrict__ coords,  // [NB, NA, 3] fp32
    const float* __restrict__ Ww,      // [FOUT, NRBF] fp32
    const float* __restrict__ Wb,      // [FOUT] fp32
    float* __restrict__ out)           // [NB, NA, NA, FOUT] fp32
{
    __shared__ float Wl[NRBF * FOUT];   // transposed: Wl[k*16 + f]
    __shared__ float Bl[FOUT];
    __shared__ float cm[256 * 3];

    const int tid   = threadIdx.x;
    const int mBase = blockIdx.x * 256;
    const int n     = blockIdx.y;
    const int b     = blockIdx.z;

    // 320 entries, 256 threads: stride so the tail 64 are written too
    for (int i = tid; i < NRBF * FOUT; i += 256) {
        int f = i / NRBF;
        int k = i - f * NRBF;
        Wl[k * FOUT + f] = Ww[i];
    }
    if (tid < FOUT) Bl[tid] = Wb[tid];

    const float* cb = coords + (size_t)b * NA * 3;
    {   // stage this block's 256 m-coordinates (768 floats) coalesced into LDS
        const float* src = cb + mBase * 3;
        cm[tid]       = src[tid];
        cm[tid + 256] = src[tid + 256];
        cm[tid + 512] = src[tid + 512];
    }
    __syncthreads();

    const float xn = cb[n * 3 + 0];
    const float yn = cb[n * 3 + 1];
    const float zn = cb[n * 3 + 2];
    const float xm = cm[tid * 3 + 0];
    const float ym = cm[tid * 3 + 1];
    const float zm = cm[tid * 3 + 2];

    const float dx = xn - xm, dy = yn - ym, dz = zn - zm;
    const float d2 = dx * dx + dy * dy + dz * dz;   // >= 0 by construction
    const float d  = sqrtf(d2);

    float acc[FOUT];
    #pragma unroll
    for (int f = 0; f < FOUT; ++f) acc[f] = Bl[f];

    #pragma unroll
    for (int k = 0; k < NRBF; ++k) {
        const float t = d - 0.1f * (float)k;
        const float r = __expf(-10.0f * t * t);
        #pragma unroll
        for (int f = 0; f < FOUT; ++f)
            acc[f] = fmaf(r, Wl[k * FOUT + f], acc[f]);
    }

    const size_t pair = ((size_t)b * NA + n) * NA + (size_t)(mBase + tid);
    float4* op = reinterpret_cast<float4*>(out + pair * FOUT);
    op[0] = make_float4(acc[0],  acc[1],  acc[2],  acc[3]);
    op[1] = make_float4(acc[4],  acc[5],  acc[6],  acc[7]);
    op[2] = make_float4(acc[8],  acc[9],  acc[10], acc[11]);
    op[3] = make_float4(acc[12], acc[13], acc[14], acc[15]);
}

extern "C" void kernel_launch(void* const* d_in, const int* in_sizes, int n_in,
                              void* d_out, int out_size, void* d_ws, size_t ws_size,
                              hipStream_t stream) {
    const float* coords = (const float*)d_in[0];
    const float* Ww     = (const float*)d_in[1];
    const float* Wb     = (const float*)d_in[2];
    float* out          = (float*)d_out;

    dim3 grid(NA / 256, NA, NB);   // (m-chunk, n, b)
    cfconv_kernel<<<grid, 256, 0, stream>>>(coords, Ww, Wb, out);
}

// Round 4
// 170.214 us; speedup vs baseline: 1.1057x; 1.1057x over previous
//
#include <hip/hip_runtime.h>

#define NRBF 20
#define FOUT 16
#define NA 768
#define NB 4

// Thread mapping (the round-3 store fix):
//   thread i computes f-quad (i&3) for m = j*64 + (i>>2), j = 0..11.
//   Its float4 store lands at tileBase + i*16B -> lane-consecutive, perfectly
//   coalesced (round-3 layout had 64B lane stride = 4x line transactions).
// W for one f-quad = 20 float4 = 80 VGPRs, preloaded once -> no LDS in hot loop.
// RBF via geometric recurrence: r_k = r_{k-1}*t_k, t_k = t_{k-1}*e^{-0.2},
//   r_0 = e^{-10 d^2}, t_1 = e^{2d-0.1}  (identity: -10(d-0.1k)^2 telescopes).

__global__ __launch_bounds__(256) void cfconv_kernel(
    const float* __restrict__ coords,  // [NB, NA, 3] fp32
    const float* __restrict__ Ww,      // [FOUT, NRBF] fp32
    const float* __restrict__ Wb,      // [FOUT] fp32
    float* __restrict__ out)           // [NB, NA, NA, FOUT] fp32
{
    __shared__ float Wt[NRBF * FOUT];      // transposed: Wt[k*16 + f]
    __shared__ float cm[NA * 3];           // all 768 m-coordinates for this batch

    const int tid = threadIdx.x;
    const int n   = blockIdx.x;
    const int b   = blockIdx.y;

    // one-time: transpose W into LDS (Ww is [f][k] row-major -> Wt[k][f])
    for (int i = tid; i < NRBF * FOUT; i += 256) {
        int k = i >> 4, f = i & 15;
        Wt[i] = Ww[f * NRBF + k];
    }
    // one-time: stage the batch's full coordinate row (2304 floats, coalesced)
    const float* cb = coords + (size_t)b * NA * 3;
    for (int i = tid; i < NA * 3; i += 256) cm[i] = cb[i];
    __syncthreads();

    const int fq   = tid & 3;     // which f-quad this thread owns
    const int mloc = tid >> 2;    // m offset within each 64-m tile

    // preload this thread's 80 W values into registers (20 float4, one time)
    float4 wk[NRBF];
    #pragma unroll
    for (int k = 0; k < NRBF; ++k)
        wk[k] = *reinterpret_cast<const float4*>(&Wt[k * FOUT + 4 * fq]);
    const float4 bias = *reinterpret_cast<const float4*>(Wb + 4 * fq);

    const float xn = cb[n * 3 + 0];
    const float yn = cb[n * 3 + 1];
    const float zn = cb[n * 3 + 2];

    const float u = 0.81873075308f;            // e^{-0.2}
    float* orow = out + ((size_t)b * NA + n) * NA * FOUT;

    #pragma unroll 4
    for (int j = 0; j < NA / 64; ++j) {
        const int m = j * 64 + mloc;
        const float dx = xn - cm[m * 3 + 0];
        const float dy = yn - cm[m * 3 + 1];
        const float dz = zn - cm[m * 3 + 2];
        const float d2 = dx * dx + dy * dy + dz * dz;
        const float d  = sqrtf(d2);

        float r = __expf(-10.0f * d2);         // r_0 = e^{-10 d^2}
        float t = __expf(2.0f * d - 0.1f);     // t_1 = e^{2d - 0.1}

        float4 a = bias;
        a.x = fmaf(r, wk[0].x, a.x);
        a.y = fmaf(r, wk[0].y, a.y);
        a.z = fmaf(r, wk[0].z, a.z);
        a.w = fmaf(r, wk[0].w, a.w);
        #pragma unroll
        for (int k = 1; k < NRBF; ++k) {
            r *= t;                            // r_k = r_{k-1} * t_k
            t *= u;                            // t_{k+1} = t_k * e^{-0.2}
            a.x = fmaf(r, wk[k].x, a.x);
            a.y = fmaf(r, wk[k].y, a.y);
            a.z = fmaf(r, wk[k].z, a.z);
            a.w = fmaf(r, wk[k].w, a.w);
        }

        // lane-consecutive float4: element offset = (j*64)*16 + tid*4
        *reinterpret_cast<float4*>(orow + (size_t)j * 64 * FOUT + tid * 4) = a;
    }
}

extern "C" void kernel_launch(void* const* d_in, const int* in_sizes, int n_in,
                              void* d_out, int out_size, void* d_ws, size_t ws_size,
                              hipStream_t stream) {
    const float* coords = (const float*)d_in[0];
    const float* Ww     = (const float*)d_in[1];
    const float* Wb     = (const float*)d_in[2];
    float* out          = (float*)d_out;

    dim3 grid(NA, NB);   // (n, b)
    cfconv_kernel<<<grid, 256, 0, stream>>>(coords, Ww, Wb, out);
}